// Round 6
// baseline (478.469 us; speedup 1.0000x reference)
//
#include <hip/hip_runtime.h>

#define T_SEQ 4096
#define D_EMB 768
#define N_HEAD 12
#define D_HEAD 64
#define D_MLP 3072
#define NTOK 8192   // B*T
#define QSCALE 0.18033688011112043f  // log2(e)/8, folded into Q at qkv epilogue

typedef __bf16 v8bf __attribute__((ext_vector_type(8)));
typedef float v4f __attribute__((ext_vector_type(4)));

template <int N> struct IC { static constexpr int value = N; };

__device__ __forceinline__ unsigned short f2bf(float f) {
    unsigned int u = __float_as_uint(f);
    unsigned int r = (u + 0x7fffu + ((u >> 16) & 1u)) >> 16;
    return (unsigned short)r;
}

__device__ __forceinline__ void g2lds16(const void* g, void* l) {
    __builtin_amdgcn_global_load_lds(
        (const __attribute__((address_space(1))) void*)g,
        (__attribute__((address_space(3))) void*)l, 16, 0, 0);
}

// ---------------- weight cast + transpose: fp32 [K][N] -> bf16 [N][K] --------
__global__ void tcast_kernel(const float* __restrict__ in, unsigned short* __restrict__ out,
                             int K, int N) {
    __shared__ float tile[32][33];
    int k0 = blockIdx.y * 32, n0 = blockIdx.x * 32;
    int tx = threadIdx.x, ty = threadIdx.y;
    for (int i = ty; i < 32; i += 8)
        tile[i][tx] = in[(size_t)(k0 + i) * N + n0 + tx];
    __syncthreads();
    for (int i = ty; i < 32; i += 8)
        out[(size_t)(n0 + i) * K + k0 + tx] = f2bf(tile[tx][i]);
}

// ------- V transpose, TILED: [bh][t][64] -> [bh][kt][64d][64k] (8KB tiles) ---
__global__ void vtrans_kernel(const unsigned short* __restrict__ in,
                              unsigned short* __restrict__ out) {
    __shared__ unsigned short tile[32][33];
    size_t base = (size_t)blockIdx.z * T_SEQ * D_HEAD;
    int t0 = blockIdx.x * 32, d0 = blockIdx.y * 32;
    int tx = threadIdx.x, ty = threadIdx.y;
    for (int i = ty; i < 32; i += 8)
        tile[i][tx] = in[base + (size_t)(t0 + i) * D_HEAD + d0 + tx];
    __syncthreads();
    size_t tbase = base + (size_t)(t0 >> 6) * 4096 + (t0 & 32);
    for (int i = ty; i < 32; i += 8)
        out[tbase + (size_t)(d0 + i) * 64 + tx] = tile[tx][i];
}

// ---------------- LayerNorm (768 wide), fp32 in -> bf16 out ------------------
__global__ __launch_bounds__(256) void ln_kernel(const float* __restrict__ x,
                                                 const float* __restrict__ g,
                                                 const float* __restrict__ bta,
                                                 unsigned short* __restrict__ out) {
    int row = blockIdx.x;
    const float* xr = x + (size_t)row * D_EMB;
    int tid = threadIdx.x;
    float v[3];
    float s = 0.f, s2 = 0.f;
#pragma unroll
    for (int i = 0; i < 3; i++) {
        v[i] = xr[tid + i * 256];
        s += v[i];
        s2 += v[i] * v[i];
    }
#pragma unroll
    for (int o = 1; o < 64; o <<= 1) {
        s += __shfl_xor(s, o);
        s2 += __shfl_xor(s2, o);
    }
    __shared__ float red[8];
    int wave = tid >> 6, lane = tid & 63;
    if (lane == 0) { red[wave] = s; red[wave + 4] = s2; }
    __syncthreads();
    s = red[0] + red[1] + red[2] + red[3];
    s2 = red[4] + red[5] + red[6] + red[7];
    float mu = s * (1.f / 768.f);
    float var = s2 * (1.f / 768.f) - mu * mu;
    float rstd = rsqrtf(var + 1e-5f);
#pragma unroll
    for (int i = 0; i < 3; i++) {
        int c = tid + i * 256;
        out[(size_t)row * D_EMB + c] = f2bf((v[i] - mu) * rstd * g[c] + bta[c]);
    }
}

// ---------------- GEMM: C[M,N] = A[M,K] * Bt[N,K]^T, bf16 in, fp32 acc -------
// (unchanged from R5: swapped-operand MFMA, dbuf global_load_lds, XCD grid)
template <int EPI>
__global__ __launch_bounds__(256) void gemm_kernel(
    const unsigned short* __restrict__ A, const unsigned short* __restrict__ Bt, int K,
    int Nt, const float* __restrict__ bias, const float* __restrict__ resid,
    float* __restrict__ outF, unsigned short* __restrict__ outB,
    unsigned short* __restrict__ Qb, unsigned short* __restrict__ Kb,
    unsigned short* __restrict__ Vb) {
    __shared__ unsigned short As[2][4096];
    __shared__ unsigned short Bs[2][4096];
    const int tid = threadIdx.x;
    const int wave = tid >> 6, lane = tid & 63;
    const int wm = wave >> 1, wn = wave & 1;
    const int n16 = lane & 15, kq = lane >> 4;
    const int id = blockIdx.x;
    const int xcd = id & 7, s = id >> 3;
    const int mt = xcd * 8 + s / Nt, nt_ = s % Nt;
    const long m0 = (long)mt * 128, nb0 = (long)nt_ * 128;

    const int c0 = (wave * 2 + 0) * 64 + lane;
    const int c1 = (wave * 2 + 1) * 64 + lane;
    const unsigned short* aP0 = A + (m0 + (c0 >> 2)) * K + ((c0 & 3) << 3);
    const unsigned short* aP1 = A + (m0 + (c1 >> 2)) * K + ((c1 & 3) << 3);
    const unsigned short* bP0 = Bt + (nb0 + (c0 >> 2)) * K + ((c0 & 3) << 3);
    const unsigned short* bP1 = Bt + (nb0 + (c1 >> 2)) * K + ((c1 & 3) << 3);
    const int fw = (wn * 64 + n16) * 32 + kq * 8;
    const int fa = (wm * 64 + n16) * 32 + kq * 8;

    const v4f vzero = {0.f, 0.f, 0.f, 0.f};
    v4f acc[4][4];
#pragma unroll
    for (int wi = 0; wi < 4; wi++)
#pragma unroll
        for (int ai = 0; ai < 4; ai++) acc[wi][ai] = vzero;

    auto stage = [&](auto BUFC, int kpos) {
        constexpr int nb = decltype(BUFC)::value;
        g2lds16(aP0 + kpos, &As[nb][(wave * 2 + 0) * 512]);
        g2lds16(aP1 + kpos, &As[nb][(wave * 2 + 1) * 512]);
        g2lds16(bP0 + kpos, &Bs[nb][(wave * 2 + 0) * 512]);
        g2lds16(bP1 + kpos, &Bs[nb][(wave * 2 + 1) * 512]);
    };
    auto gstep = [&](auto BUFC, int kpos, bool pref) {
        constexpr int buf = decltype(BUFC)::value;
        __syncthreads();
        if (pref) stage(IC<buf ^ 1>{}, kpos + 32);
        v8bf wf[4], af[4];
#pragma unroll
        for (int i = 0; i < 4; i++) {
            wf[i] = *(const v8bf*)(&Bs[buf][fw + i * 512]);
            af[i] = *(const v8bf*)(&As[buf][fa + i * 512]);
        }
#pragma unroll
        for (int wi = 0; wi < 4; wi++)
#pragma unroll
            for (int ai = 0; ai < 4; ai++)
                acc[wi][ai] = __builtin_amdgcn_mfma_f32_16x16x32_bf16(wf[wi], af[ai],
                                                                     acc[wi][ai], 0, 0, 0);
    };

    stage(IC<0>{}, 0);
#pragma unroll 1
    for (int k0 = 0; k0 < K; k0 += 64) {
        gstep(IC<0>{}, k0, true);
        gstep(IC<1>{}, k0 + 32, k0 + 64 < K);
    }

#pragma unroll
    for (int wi = 0; wi < 4; wi++) {
#pragma unroll
        for (int ai = 0; ai < 4; ai++) {
            const long Nb = nb0 + wn * 64 + wi * 16 + kq * 4;
            const long M = m0 + wm * 64 + ai * 16 + n16;
            if (EPI == 0) {
                int which = (int)(Nb / 768);
                int c = (int)(Nb - which * 768);
                int hh = c >> 6, ii = c & 63;
                int bb = (int)(M >> 12), t = (int)(M & 4095);
                size_t dst = (((size_t)bb * N_HEAD + hh) * T_SEQ + t) * D_HEAD + ii;
                union { uint2 u2; unsigned short us[4]; } pk;
#pragma unroll
                for (int r = 0; r < 4; r++) {
                    float v = acc[wi][ai][r];
                    if (which == 0) v *= QSCALE;
                    pk.us[r] = f2bf(v);
                }
                if (which == 0) *(uint2*)(&Qb[dst]) = pk.u2;
                else if (which == 1) *(uint2*)(&Kb[dst]) = pk.u2;
                else *(uint2*)(&Vb[dst]) = pk.u2;
            } else if (EPI == 1) {
                float4 b4 = *(const float4*)(&bias[Nb]);
                float4 r4 = *(const float4*)(&resid[M * 768 + Nb]);
                float4 o4;
                o4.x = acc[wi][ai][0] + b4.x + r4.x;
                o4.y = acc[wi][ai][1] + b4.y + r4.y;
                o4.z = acc[wi][ai][2] + b4.z + r4.z;
                o4.w = acc[wi][ai][3] + b4.w + r4.w;
                *(float4*)(&outF[M * 768 + Nb]) = o4;
            } else {
                float4 b4 = *(const float4*)(&bias[Nb]);
                union { uint2 u2; unsigned short us[4]; } pk;
#pragma unroll
                for (int r = 0; r < 4; r++) {
                    float t = acc[wi][ai][r] + ((const float*)&b4)[r];
                    pk.us[r] = f2bf(0.5f * t * (1.f + erff(t * 0.70710678118f)));
                }
                *(uint2*)(&outB[M * 3072 + Nb]) = pk.u2;
            }
        }
    }
}

// ---------------- Flash attention (causal), bf16 Q/K/Vt -> bf16 y ------------
// 128-query blocks: each wave owns 32 q (two 16-q subtiles) -> shared K/V
// fragment reads amortized over 2x query work (attn was LDS-pipe bound).
// No pairing; 768 blocks (3/CU), largest-first order for dynamic balance.
// S^T trick, pre-scaled Q, l via ones-MFMA, wave-private P, dbuf staging.
#define PSTR 72
__global__ __launch_bounds__(256) void attn_kernel(const unsigned short* __restrict__ Q,
                                                   const unsigned short* __restrict__ Kg,
                                                   const unsigned short* __restrict__ Vt,
                                                   unsigned short* __restrict__ y) {
    __shared__ unsigned short Kt[2][4096];
    __shared__ unsigned short Vl[2][4096];
    __shared__ unsigned short Ps[4][2][16 * PSTR];
    const int tid = threadIdx.x;
    const int wave = tid >> 6, lane = tid & 63;
    const int n16 = lane & 15, kq = lane >> 4;
    // id&7 = XCD (3 bh-combos each); within stripe: largest q-tile first
    const int id = blockIdx.x;
    const int xcd = id & 7, slot = id >> 3;
    const int combo = xcd * 3 + (slot >> 5);
    const int j = 31 - (slot & 31);          // q-tile index, 128 queries
    const int h = combo % N_HEAD, b = combo / N_HEAD;
    const size_t hoff = (((size_t)b * N_HEAD + h) * T_SEQ) * D_HEAD;
    const unsigned short* Qh = Q + hoff;
    const unsigned short* Kh = Kg + hoff;   // [t][64], k-tile contiguous 8KB
    const unsigned short* Vh = Vt + hoff;   // [kt][64][64] tiled
    const v4f vzero = {0.f, 0.f, 0.f, 0.f};

    const int sC0 = (wave * 2 + 0) * 64 + lane;
    const int sC1 = (wave * 2 + 1) * 64 + lane;
    const int soff0 = (sC0 >> 3) * 64 + ((((sC0 & 7) ^ ((sC0 >> 3) & 7))) << 3);
    const int soff1 = (sC1 >> 3) * 64 + ((((sC1 & 7) ^ ((sC1 >> 3) & 7))) << 3);
    const int fb0 = n16 * 64 + ((kq ^ (n16 & 7)) << 3);
    const int fb1 = n16 * 64 + (((4 + kq) ^ (n16 & 7)) << 3);
    unsigned short* pwr0 = &Ps[wave][0][n16 * PSTR + kq * 4];
    unsigned short* pwr1 = &Ps[wave][1][n16 * PSTR + kq * 4];
    const unsigned short* prd0 = &Ps[wave][0][n16 * PSTR + kq * 8];
    const unsigned short* prd1 = &Ps[wave][1][n16 * PSTR + kq * 8];
    v8bf vone;
#pragma unroll
    for (int jj = 0; jj < 8; jj++) ((unsigned short*)&vone)[jj] = 0x3F80;  // 1.0bf

    const int nsteps = 2 * j + 2;            // always even
    const int qg0 = j * 128 + wave * 32 + n16;
    const int qg1 = qg0 + 16;
    v8bf qf[2][2];
#pragma unroll
    for (int q16 = 0; q16 < 2; q16++)
#pragma unroll
        for (int ks = 0; ks < 2; ks++)
            qf[q16][ks] = *(const v8bf*)(
                &Qh[(size_t)(qg0 + q16 * 16) * D_HEAD + ks * 32 + kq * 8]);

    v4f o[2][4], lacc[2];
#pragma unroll
    for (int q16 = 0; q16 < 2; q16++) {
        lacc[q16] = vzero;
#pragma unroll
        for (int nt = 0; nt < 4; nt++) o[q16][nt] = vzero;
    }

    const unsigned short* knext = Kh + 4096;
    const unsigned short* vnext = Vh + 4096;
    // stage kt=0 into buf0 (no prior LDS readers -> no barrier needed first)
    g2lds16(Kh + soff0, &Kt[0][(wave * 2 + 0) * 512]);
    g2lds16(Kh + soff1, &Kt[0][(wave * 2 + 1) * 512]);
    g2lds16(Vh + soff0, &Vl[0][(wave * 2 + 0) * 512]);
    g2lds16(Vh + soff1, &Vl[0][(wave * 2 + 1) * 512]);

    auto step = [&](auto BUFC, int kt, bool pref, bool diag) {
        constexpr int buf = decltype(BUFC)::value;
        __syncthreads();  // buf tiles ready (vmcnt), all waves past prev reads
        if (pref) {
            g2lds16(knext + soff0, &Kt[buf ^ 1][(wave * 2 + 0) * 512]);
            g2lds16(knext + soff1, &Kt[buf ^ 1][(wave * 2 + 1) * 512]);
            g2lds16(vnext + soff0, &Vl[buf ^ 1][(wave * 2 + 0) * 512]);
            g2lds16(vnext + soff1, &Vl[buf ^ 1][(wave * 2 + 1) * 512]);
            knext += 4096;
            vnext += 4096;
        }
        // S^T = K * Q^T for both q-subtiles (K frags shared)
#pragma unroll
        for (int q16 = 0; q16 < 2; q16++) {
            v4f s[4];
#pragma unroll
            for (int nt = 0; nt < 4; nt++) s[nt] = vzero;
#pragma unroll
            for (int nt = 0; nt < 4; nt++) {
                v8bf k0 = *(const v8bf*)(&Kt[buf][nt * 1024 + fb0]);
                v8bf k1 = *(const v8bf*)(&Kt[buf][nt * 1024 + fb1]);
                s[nt] = __builtin_amdgcn_mfma_f32_16x16x32_bf16(k0, qf[q16][0], s[nt], 0, 0, 0);
                s[nt] = __builtin_amdgcn_mfma_f32_16x16x32_bf16(k1, qf[q16][1], s[nt], 0, 0, 0);
            }
            const int qg = q16 ? qg1 : qg0;
            unsigned short* pw = q16 ? pwr1 : pwr0;
#pragma unroll
            for (int nt = 0; nt < 4; nt++) {
                union { uint2 u2; __bf16 hh[4]; } pk;
#pragma unroll
                for (int r = 0; r < 4; r++) {
                    float p = __builtin_amdgcn_exp2f(s[nt][r]);
                    if (diag) {
                        int key = kt * 64 + nt * 16 + kq * 4 + r;
                        if (key > qg) p = 0.f;
                    }
                    pk.hh[r] = (__bf16)p;
                }
                *(uint2*)(&pw[nt * 16]) = pk.u2;
            }
        }
        // O += P*V ; l += P*1   (V frags shared across q-subtiles)
#pragma unroll
        for (int ks = 0; ks < 2; ks++) {
            v8bf pa0 = *(const v8bf*)(&prd0[ks * 32]);
            v8bf pa1 = *(const v8bf*)(&prd1[ks * 32]);
            lacc[0] = __builtin_amdgcn_mfma_f32_16x16x32_bf16(pa0, vone, lacc[0], 0, 0, 0);
            lacc[1] = __builtin_amdgcn_mfma_f32_16x16x32_bf16(pa1, vone, lacc[1], 0, 0, 0);
#pragma unroll
            for (int nt = 0; nt < 4; nt++) {
                v8bf vb = *(const v8bf*)(&Vl[buf][nt * 1024 + (ks ? fb1 : fb0)]);
                o[0][nt] = __builtin_amdgcn_mfma_f32_16x16x32_bf16(pa0, vb, o[0][nt], 0, 0, 0);
                o[1][nt] = __builtin_amdgcn_mfma_f32_16x16x32_bf16(pa1, vb, o[1][nt], 0, 0, 0);
            }
        }
    };

#pragma unroll 1
    for (int kt = 0; kt < nsteps; kt += 2) {
        const bool lastp = (kt + 2 >= nsteps);
        step(IC<0>{}, kt, true, lastp);
        step(IC<1>{}, kt + 1, !lastp, lastp);
    }

#pragma unroll
    for (int q16 = 0; q16 < 2; q16++) {
        float linv[4];
#pragma unroll
        for (int r = 0; r < 4; r++) linv[r] = 1.f / lacc[q16][r];
#pragma unroll
        for (int nt = 0; nt < 4; nt++)
#pragma unroll
            for (int r = 0; r < 4; r++) {
                int q = j * 128 + wave * 32 + q16 * 16 + kq * 4 + r;
                float val = o[q16][nt][r] * linv[r];
                y[((size_t)b * T_SEQ + q) * D_EMB + h * 64 + nt * 16 + n16] = f2bf(val);
            }
    }
}

// ---------------- launch -----------------------------------------------------
extern "C" void kernel_launch(void* const* d_in, const int* in_sizes, int n_in,
                              void* d_out, int out_size, void* d_ws, size_t ws_size,
                              hipStream_t stream) {
    const float* x = (const float*)d_in[0];
    const float* ln1_g = (const float*)d_in[1];
    const float* ln1_b = (const float*)d_in[2];
    const float* wqkv_w = (const float*)d_in[3];
    const float* wo_w = (const float*)d_in[4];
    const float* wo_b = (const float*)d_in[5];
    const float* ln2_g = (const float*)d_in[6];
    const float* ln2_b = (const float*)d_in[7];
    const float* w1_w = (const float*)d_in[8];
    const float* w1_b = (const float*)d_in[9];
    const float* w2_w = (const float*)d_in[10];
    const float* w2_b = (const float*)d_in[11];
    float* out = (float*)d_out;

    char* ws = (char*)d_ws;
    size_t off = 0;
    auto alloc = [&](size_t bytes) -> void* {
        void* p = ws + off;
        off += (bytes + 255) & ~(size_t)255;
        return p;
    };
    unsigned short* xn = (unsigned short*)alloc((size_t)NTOK * D_EMB * 2);
    unsigned short* wqkvT = (unsigned short*)alloc((size_t)2304 * 768 * 2);
    unsigned short* woT = (unsigned short*)alloc((size_t)768 * 768 * 2);
    unsigned short* w1T = (unsigned short*)alloc((size_t)3072 * 768 * 2);
    unsigned short* w2T = (unsigned short*)alloc((size_t)768 * 3072 * 2);
    unsigned short* Qb = (unsigned short*)alloc((size_t)NTOK * D_EMB * 2);
    unsigned short* Kb = (unsigned short*)alloc((size_t)NTOK * D_EMB * 2);
    unsigned short* Vb = (unsigned short*)alloc((size_t)NTOK * D_EMB * 2);
    unsigned short* yb = (unsigned short*)alloc((size_t)NTOK * D_EMB * 2);
    float* res1 = (float*)alloc((size_t)NTOK * D_EMB * 4);
    unsigned short* Vtb = xn;   // V^T overlay: xn dead during attn
    unsigned short* hbuf = Qb;  // w1 out overlay: spans Qb..yb (all dead then)

    dim3 tb(32, 8);
    tcast_kernel<<<dim3(2304 / 32, 768 / 32), tb, 0, stream>>>(wqkv_w, wqkvT, 768, 2304);
    tcast_kernel<<<dim3(768 / 32, 768 / 32), tb, 0, stream>>>(wo_w, woT, 768, 768);
    tcast_kernel<<<dim3(3072 / 32, 768 / 32), tb, 0, stream>>>(w1_w, w1T, 768, 3072);
    tcast_kernel<<<dim3(768 / 32, 3072 / 32), tb, 0, stream>>>(w2_w, w2T, 3072, 768);

    ln_kernel<<<NTOK, 256, 0, stream>>>(x, ln1_g, ln1_b, xn);

    gemm_kernel<0><<<64 * 18, 256, 0, stream>>>(
        xn, wqkvT, 768, 18, nullptr, nullptr, nullptr, nullptr, Qb, Kb, Vb);

    vtrans_kernel<<<dim3(T_SEQ / 32, 2, 2 * N_HEAD), tb, 0, stream>>>(Vb, Vtb);

    attn_kernel<<<768, 256, 0, stream>>>(Qb, Kb, Vtb, yb);

    gemm_kernel<1><<<64 * 6, 256, 0, stream>>>(
        yb, woT, 768, 6, wo_b, x, res1, nullptr, nullptr, nullptr, nullptr);

    ln_kernel<<<NTOK, 256, 0, stream>>>(res1, ln2_g, ln2_b, xn);

    gemm_kernel<2><<<64 * 24, 256, 0, stream>>>(
        xn, w1T, 768, 24, w1_b, nullptr, nullptr, hbuf, nullptr, nullptr, nullptr);

    gemm_kernel<1><<<64 * 6, 256, 0, stream>>>(
        hbuf, w2T, 3072, 6, w2_b, res1, out, nullptr, nullptr, nullptr, nullptr);
}

// Round 8
// 455.928 us; speedup vs baseline: 1.0494x; 1.0494x over previous
//
#include <hip/hip_runtime.h>

#define T_SEQ 4096
#define D_EMB 768
#define N_HEAD 12
#define D_HEAD 64
#define D_MLP 3072
#define NTOK 8192   // B*T
#define QSCALE 0.18033688011112043f  // log2(e)/8, folded into Q at qkv epilogue

typedef __bf16 v8bf __attribute__((ext_vector_type(8)));
typedef float v4f __attribute__((ext_vector_type(4)));

template <int N> struct IC { static constexpr int value = N; };

__device__ __forceinline__ unsigned short f2bf(float f) {
    unsigned int u = __float_as_uint(f);
    unsigned int r = (u + 0x7fffu + ((u >> 16) & 1u)) >> 16;
    return (unsigned short)r;
}

__device__ __forceinline__ void g2lds16(const void* g, void* l) {
    __builtin_amdgcn_global_load_lds(
        (const __attribute__((address_space(1))) void*)g,
        (__attribute__((address_space(3))) void*)l, 16, 0, 0);
}

// ---------------- weight cast + transpose: fp32 [K][N] -> bf16 [N][K] --------
__global__ void tcast_kernel(const float* __restrict__ in, unsigned short* __restrict__ out,
                             int K, int N) {
    __shared__ float tile[32][33];
    int k0 = blockIdx.y * 32, n0 = blockIdx.x * 32;
    int tx = threadIdx.x, ty = threadIdx.y;
    for (int i = ty; i < 32; i += 8)
        tile[i][tx] = in[(size_t)(k0 + i) * N + n0 + tx];
    __syncthreads();
    for (int i = ty; i < 32; i += 8)
        out[(size_t)(n0 + i) * K + k0 + tx] = f2bf(tile[tx][i]);
}

// ------- V transpose, TILED: [bh][t][64] -> [bh][kt][64d][64k] (8KB tiles) ---
__global__ void vtrans_kernel(const unsigned short* __restrict__ in,
                              unsigned short* __restrict__ out) {
    __shared__ unsigned short tile[32][33];
    size_t base = (size_t)blockIdx.z * T_SEQ * D_HEAD;
    int t0 = blockIdx.x * 32, d0 = blockIdx.y * 32;
    int tx = threadIdx.x, ty = threadIdx.y;
    for (int i = ty; i < 32; i += 8)
        tile[i][tx] = in[base + (size_t)(t0 + i) * D_HEAD + d0 + tx];
    __syncthreads();
    size_t tbase = base + (size_t)(t0 >> 6) * 4096 + (t0 & 32);
    for (int i = ty; i < 32; i += 8)
        out[tbase + (size_t)(d0 + i) * 64 + tx] = tile[tx][i];
}

// ---------------- LayerNorm (768 wide), fp32 in -> bf16 out ------------------
__global__ __launch_bounds__(256) void ln_kernel(const float* __restrict__ x,
                                                 const float* __restrict__ g,
                                                 const float* __restrict__ bta,
                                                 unsigned short* __restrict__ out) {
    int row = blockIdx.x;
    const float* xr = x + (size_t)row * D_EMB;
    int tid = threadIdx.x;
    float v[3];
    float s = 0.f, s2 = 0.f;
#pragma unroll
    for (int i = 0; i < 3; i++) {
        v[i] = xr[tid + i * 256];
        s += v[i];
        s2 += v[i] * v[i];
    }
#pragma unroll
    for (int o = 1; o < 64; o <<= 1) {
        s += __shfl_xor(s, o);
        s2 += __shfl_xor(s2, o);
    }
    __shared__ float red[8];
    int wave = tid >> 6, lane = tid & 63;
    if (lane == 0) { red[wave] = s; red[wave + 4] = s2; }
    __syncthreads();
    s = red[0] + red[1] + red[2] + red[3];
    s2 = red[4] + red[5] + red[6] + red[7];
    float mu = s * (1.f / 768.f);
    float var = s2 * (1.f / 768.f) - mu * mu;
    float rstd = rsqrtf(var + 1e-5f);
#pragma unroll
    for (int i = 0; i < 3; i++) {
        int c = tid + i * 256;
        out[(size_t)row * D_EMB + c] = f2bf((v[i] - mu) * rstd * g[c] + bta[c]);
    }
}

// ---------------- GEMM: C[M,N] = A[M,K] * Bt[N,K]^T, bf16 in, fp32 acc -------
// Swapped-operand MFMA; dbuf global_load_lds staging; XCD-striped 1-D grid.
// MT=128: 128x128 tile (acc 4x4). MT=64: 64x128 tile (acc 4x2, 24KB LDS,
// 6 blocks/CU) -- used where N-tile count makes 128-tiles mis-quantized.
// A-tile chunk index differs by MT: MT=128 -> 512 chunks (2/thread),
// MT=64 -> 256 chunks (1/thread, c = wave*64+lane).  [R7 bug: used B's index]
template <int EPI, int MT>
__global__ __launch_bounds__(256) void gemm_kernel(
    const unsigned short* __restrict__ A, const unsigned short* __restrict__ Bt, int K,
    int Nt, const float* __restrict__ bias, const float* __restrict__ resid,
    float* __restrict__ outF, unsigned short* __restrict__ outB,
    unsigned short* __restrict__ Qb, unsigned short* __restrict__ Kb,
    unsigned short* __restrict__ Vb) {
    constexpr int NAI = (MT == 128) ? 4 : 2;     // act M-subtiles per wave
    __shared__ unsigned short As[2][MT * 32];
    __shared__ unsigned short Bs[2][4096];
    const int tid = threadIdx.x;
    const int wave = tid >> 6, lane = tid & 63;
    const int n16 = lane & 15, kq = lane >> 4;
    const int moff = (wave >> 1) * (MT / 2), noff = (wave & 1) * 64;
    // grid decode: (NTOK/MT)/8 M-tiles per XCD stripe; N inner
    const int id = blockIdx.x;
    const int xcd = id & 7, s = id >> 3;
    const int mt = xcd * (NTOK / MT / 8) + s / Nt, nt_ = s % Nt;
    const long m0 = (long)mt * MT, nb0 = (long)nt_ * 128;

    // staging thread-constants
    const int c0 = (wave * 2 + 0) * 64 + lane;   // B: 512 chunks, 2/thread
    const int c1 = (wave * 2 + 1) * 64 + lane;
    const unsigned short* bP0 = Bt + (nb0 + (c0 >> 2)) * K + ((c0 & 3) << 3);
    const unsigned short* bP1 = Bt + (nb0 + (c1 >> 2)) * K + ((c1 & 3) << 3);
    const int ca = (MT == 128) ? c0 : (wave * 64 + lane);  // A chunk index
    const unsigned short* aP0 = A + (m0 + (ca >> 2)) * K + ((ca & 3) << 3);
    const unsigned short* aP1 = (MT == 128)
        ? A + (m0 + (c1 >> 2)) * K + ((c1 & 3) << 3) : nullptr;
    // fragment LDS short-indices (loop-invariant)
    const int fw = (noff + n16) * 32 + kq * 8;   // weight frags from Bs
    const int fa = (moff + n16) * 32 + kq * 8;   // act frags from As

    const v4f vzero = {0.f, 0.f, 0.f, 0.f};
    v4f acc[4][NAI];
#pragma unroll
    for (int wi = 0; wi < 4; wi++)
#pragma unroll
        for (int ai = 0; ai < NAI; ai++) acc[wi][ai] = vzero;

    auto stage = [&](auto BUFC, int kpos) {
        constexpr int nb = decltype(BUFC)::value;
        if (MT == 128) {
            g2lds16(aP0 + kpos, &As[nb][(wave * 2 + 0) * 512]);
            g2lds16(aP1 + kpos, &As[nb][(wave * 2 + 1) * 512]);
        } else {
            g2lds16(aP0 + kpos, &As[nb][wave * 512]);  // chunks wave*64..+63
        }
        g2lds16(bP0 + kpos, &Bs[nb][(wave * 2 + 0) * 512]);
        g2lds16(bP1 + kpos, &Bs[nb][(wave * 2 + 1) * 512]);
    };
    auto gstep = [&](auto BUFC, int kpos, bool pref) {
        constexpr int buf = decltype(BUFC)::value;
        __syncthreads();
        if (pref) stage(IC<buf ^ 1>{}, kpos + 32);
        v8bf wf[4], af[NAI];
#pragma unroll
        for (int i = 0; i < 4; i++) wf[i] = *(const v8bf*)(&Bs[buf][fw + i * 512]);
#pragma unroll
        for (int i = 0; i < NAI; i++) af[i] = *(const v8bf*)(&As[buf][fa + i * 512]);
#pragma unroll
        for (int wi = 0; wi < 4; wi++)
#pragma unroll
            for (int ai = 0; ai < NAI; ai++)
                acc[wi][ai] = __builtin_amdgcn_mfma_f32_16x16x32_bf16(wf[wi], af[ai],
                                                                     acc[wi][ai], 0, 0, 0);
    };

    stage(IC<0>{}, 0);
#pragma unroll 1
    for (int k0 = 0; k0 < K; k0 += 64) {
        gstep(IC<0>{}, k0, true);
        gstep(IC<1>{}, k0 + 32, k0 + 64 < K);
    }

#pragma unroll
    for (int wi = 0; wi < 4; wi++) {
#pragma unroll
        for (int ai = 0; ai < NAI; ai++) {
            const long Nb = nb0 + noff + wi * 16 + kq * 4;
            const long M = m0 + moff + ai * 16 + n16;
            if (EPI == 0) {
                int which = (int)(Nb / 768);
                int c = (int)(Nb - which * 768);
                int hh = c >> 6, ii = c & 63;
                int bb = (int)(M >> 12), t = (int)(M & 4095);
                size_t dst = (((size_t)bb * N_HEAD + hh) * T_SEQ + t) * D_HEAD + ii;
                union { uint2 u2; unsigned short us[4]; } pk;
#pragma unroll
                for (int r = 0; r < 4; r++) {
                    float v = acc[wi][ai][r];
                    if (which == 0) v *= QSCALE;
                    pk.us[r] = f2bf(v);
                }
                if (which == 0) *(uint2*)(&Qb[dst]) = pk.u2;
                else if (which == 1) *(uint2*)(&Kb[dst]) = pk.u2;
                else *(uint2*)(&Vb[dst]) = pk.u2;
            } else if (EPI == 1) {
                float4 b4 = *(const float4*)(&bias[Nb]);
                float4 r4 = *(const float4*)(&resid[M * 768 + Nb]);
                float4 o4;
                o4.x = acc[wi][ai][0] + b4.x + r4.x;
                o4.y = acc[wi][ai][1] + b4.y + r4.y;
                o4.z = acc[wi][ai][2] + b4.z + r4.z;
                o4.w = acc[wi][ai][3] + b4.w + r4.w;
                *(float4*)(&outF[M * 768 + Nb]) = o4;
            } else {
                float4 b4 = *(const float4*)(&bias[Nb]);
                union { uint2 u2; unsigned short us[4]; } pk;
#pragma unroll
                for (int r = 0; r < 4; r++) {
                    float t = acc[wi][ai][r] + ((const float*)&b4)[r];
                    pk.us[r] = f2bf(0.5f * t * (1.f + erff(t * 0.70710678118f)));
                }
                *(uint2*)(&outB[M * 3072 + Nb]) = pk.u2;
            }
        }
    }
}

// ---------------- Flash attention (causal), bf16 Q/K/Vt -> bf16 y ------------
// R5 kernel (verified 98us): 64-q blocks, PAIRED q-tiles (qt, 63-qt) -> 65
// uniform steps/block; S^T trick, pre-scaled Q, l via ones-MFMA, manual
// unroll-2 (compile-time buf), wave-private P, dbuf K/V staging.
#define PSTR 72
__global__ __launch_bounds__(256) void attn_kernel(const unsigned short* __restrict__ Q,
                                                   const unsigned short* __restrict__ Kg,
                                                   const unsigned short* __restrict__ Vt,
                                                   unsigned short* __restrict__ y) {
    __shared__ unsigned short Kt[2][4096];
    __shared__ unsigned short Vl[2][4096];
    __shared__ unsigned short Ps[4 * 16 * PSTR];
    const int tid = threadIdx.x;
    const int wave = tid >> 6, lane = tid & 63;
    const int n16 = lane & 15, kq = lane >> 4;
    const int id = blockIdx.x;
    const int xcd = id & 7, slot = id >> 3;
    const int combo = xcd * 3 + (slot >> 5);
    const int pair = slot & 31;
    const int h = combo % N_HEAD, b = combo / N_HEAD;
    const size_t hoff = (((size_t)b * N_HEAD + h) * T_SEQ) * D_HEAD;
    const unsigned short* Qh = Q + hoff;
    const unsigned short* Kh = Kg + hoff;   // [t][64], k-tile contiguous 8KB
    const unsigned short* Vh = Vt + hoff;   // [kt][64][64] tiled
    const v4f vzero = {0.f, 0.f, 0.f, 0.f};

    const int sC0 = (wave * 2 + 0) * 64 + lane;
    const int sC1 = (wave * 2 + 1) * 64 + lane;
    const int soff0 = (sC0 >> 3) * 64 + ((((sC0 & 7) ^ ((sC0 >> 3) & 7))) << 3);
    const int soff1 = (sC1 >> 3) * 64 + ((((sC1 & 7) ^ ((sC1 >> 3) & 7))) << 3);
    const int fb0 = n16 * 64 + ((kq ^ (n16 & 7)) << 3);
    const int fb1 = n16 * 64 + (((4 + kq) ^ (n16 & 7)) << 3);
    unsigned short* pwr = &Ps[wave * 1152 + n16 * PSTR + kq * 4];
    const unsigned short* prd = &Ps[wave * 1152 + n16 * PSTR + kq * 8];
    v8bf vone;
#pragma unroll
    for (int j = 0; j < 8; j++) ((unsigned short*)&vone)[j] = 0x3F80;  // bf16 1.0

    const unsigned short* knext;
    const unsigned short* vnext;
    v4f o[4], lacc;
    int qt, qglob;
    v8bf qf[2];

    auto step = [&](auto BUFC, int kt, bool pref, bool diag) {
        constexpr int buf = decltype(BUFC)::value;
        __syncthreads();  // buf's tiles ready (vmcnt), prev reads done (lgkm)
        if (pref) {
            g2lds16(knext + soff0, &Kt[buf ^ 1][(wave * 2 + 0) * 512]);
            g2lds16(knext + soff1, &Kt[buf ^ 1][(wave * 2 + 1) * 512]);
            g2lds16(vnext + soff0, &Vl[buf ^ 1][(wave * 2 + 0) * 512]);
            g2lds16(vnext + soff1, &Vl[buf ^ 1][(wave * 2 + 1) * 512]);
            knext += 4096;
            vnext += 4096;
        }
        v4f s[4];
#pragma unroll
        for (int nt = 0; nt < 4; nt++) s[nt] = vzero;
#pragma unroll
        for (int nt = 0; nt < 4; nt++) {
            v8bf k0 = *(const v8bf*)(&Kt[buf][nt * 1024 + fb0]);
            v8bf k1 = *(const v8bf*)(&Kt[buf][nt * 1024 + fb1]);
            s[nt] = __builtin_amdgcn_mfma_f32_16x16x32_bf16(k0, qf[0], s[nt], 0, 0, 0);
            s[nt] = __builtin_amdgcn_mfma_f32_16x16x32_bf16(k1, qf[1], s[nt], 0, 0, 0);
        }
#pragma unroll
        for (int nt = 0; nt < 4; nt++) {
            union { uint2 u2; __bf16 hh[4]; } pk;
#pragma unroll
            for (int r = 0; r < 4; r++) {
                float p = __builtin_amdgcn_exp2f(s[nt][r]);
                if (diag) {
                    int key = kt * 64 + nt * 16 + kq * 4 + r;
                    if (key > qglob) p = 0.f;
                }
                pk.hh[r] = (__bf16)p;
            }
            *(uint2*)(&pwr[nt * 16]) = pk.u2;
        }
#pragma unroll
        for (int ks = 0; ks < 2; ks++) {
            v8bf pa = *(const v8bf*)(&prd[ks * 32]);
            lacc = __builtin_amdgcn_mfma_f32_16x16x32_bf16(pa, vone, lacc, 0, 0, 0);
#pragma unroll
            for (int nt = 0; nt < 4; nt++) {
                v8bf vb = *(const v8bf*)(&Vl[buf][nt * 1024 + (ks ? fb1 : fb0)]);
                o[nt] = __builtin_amdgcn_mfma_f32_16x16x32_bf16(pa, vb, o[nt], 0, 0, 0);
            }
        }
    };

#pragma unroll 1
    for (int half = 0; half < 2; half++) {
        qt = half ? (63 - pair) : pair;
        qglob = qt * 64 + wave * 16 + n16;
#pragma unroll
        for (int ks = 0; ks < 2; ks++)
            qf[ks] = *(const v8bf*)(&Qh[(size_t)qglob * D_HEAD + ks * 32 + kq * 8]);
#pragma unroll
        for (int nt = 0; nt < 4; nt++) o[nt] = vzero;
        lacc = vzero;

        __syncthreads();  // prev half's readers done before restaging buf0
        g2lds16(Kh + soff0, &Kt[0][(wave * 2 + 0) * 512]);
        g2lds16(Kh + soff1, &Kt[0][(wave * 2 + 1) * 512]);
        g2lds16(Vh + soff0, &Vl[0][(wave * 2 + 0) * 512]);
        g2lds16(Vh + soff1, &Vl[0][(wave * 2 + 1) * 512]);
        knext = Kh + 4096;
        vnext = Vh + 4096;

        int kt = 0;
#pragma unroll 1
        while (kt + 2 <= qt) {
            step(IC<0>{}, kt, true, false);
            step(IC<1>{}, kt + 1, true, false);
            kt += 2;
        }
        if (kt < qt) {
            step(IC<0>{}, kt, true, false);
            step(IC<1>{}, kt + 1, false, true);
        } else {
            step(IC<0>{}, kt, false, true);
        }

        float linv[4];
#pragma unroll
        for (int r = 0; r < 4; r++) linv[r] = 1.f / lacc[r];
#pragma unroll
        for (int nt = 0; nt < 4; nt++)
#pragma unroll
            for (int r = 0; r < 4; r++) {
                int q = qt * 64 + wave * 16 + kq * 4 + r;
                float val = o[nt][r] * linv[r];
                y[((size_t)b * T_SEQ + q) * D_EMB + h * 64 + nt * 16 + n16] = f2bf(val);
            }
    }
}

// ---------------- launch -----------------------------------------------------
extern "C" void kernel_launch(void* const* d_in, const int* in_sizes, int n_in,
                              void* d_out, int out_size, void* d_ws, size_t ws_size,
                              hipStream_t stream) {
    const float* x = (const float*)d_in[0];
    const float* ln1_g = (const float*)d_in[1];
    const float* ln1_b = (const float*)d_in[2];
    const float* wqkv_w = (const float*)d_in[3];
    const float* wo_w = (const float*)d_in[4];
    const float* wo_b = (const float*)d_in[5];
    const float* ln2_g = (const float*)d_in[6];
    const float* ln2_b = (const float*)d_in[7];
    const float* w1_w = (const float*)d_in[8];
    const float* w1_b = (const float*)d_in[9];
    const float* w2_w = (const float*)d_in[10];
    const float* w2_b = (const float*)d_in[11];
    float* out = (float*)d_out;

    char* ws = (char*)d_ws;
    size_t off = 0;
    auto alloc = [&](size_t bytes) -> void* {
        void* p = ws + off;
        off += (bytes + 255) & ~(size_t)255;
        return p;
    };
    unsigned short* xn = (unsigned short*)alloc((size_t)NTOK * D_EMB * 2);
    unsigned short* wqkvT = (unsigned short*)alloc((size_t)2304 * 768 * 2);
    unsigned short* woT = (unsigned short*)alloc((size_t)768 * 768 * 2);
    unsigned short* w1T = (unsigned short*)alloc((size_t)3072 * 768 * 2);
    unsigned short* w2T = (unsigned short*)alloc((size_t)768 * 3072 * 2);
    unsigned short* Qb = (unsigned short*)alloc((size_t)NTOK * D_EMB * 2);
    unsigned short* Kb = (unsigned short*)alloc((size_t)NTOK * D_EMB * 2);
    unsigned short* Vb = (unsigned short*)alloc((size_t)NTOK * D_EMB * 2);
    unsigned short* yb = (unsigned short*)alloc((size_t)NTOK * D_EMB * 2);
    float* res1 = (float*)alloc((size_t)NTOK * D_EMB * 4);
    unsigned short* Vtb = xn;   // V^T overlay: xn dead during attn
    unsigned short* hbuf = Qb;  // w1 out overlay: spans Qb..yb (all dead then)

    dim3 tb(32, 8);
    tcast_kernel<<<dim3(2304 / 32, 768 / 32), tb, 0, stream>>>(wqkv_w, wqkvT, 768, 2304);
    tcast_kernel<<<dim3(768 / 32, 768 / 32), tb, 0, stream>>>(wo_w, woT, 768, 768);
    tcast_kernel<<<dim3(3072 / 32, 768 / 32), tb, 0, stream>>>(w1_w, w1T, 768, 3072);
    tcast_kernel<<<dim3(768 / 32, 3072 / 32), tb, 0, stream>>>(w2_w, w2T, 3072, 768);

    ln_kernel<<<NTOK, 256, 0, stream>>>(x, ln1_g, ln1_b, xn);

    gemm_kernel<0, 64><<<2304, 256, 0, stream>>>(     // 9 blocks/CU exact
        xn, wqkvT, 768, 18, nullptr, nullptr, nullptr, nullptr, Qb, Kb, Vb);

    vtrans_kernel<<<dim3(T_SEQ / 32, 2, 2 * N_HEAD), tb, 0, stream>>>(Vb, Vtb);

    attn_kernel<<<768, 256, 0, stream>>>(Qb, Kb, Vtb, yb);

    gemm_kernel<1, 64><<<768, 256, 0, stream>>>(      // 3 blocks/CU exact
        yb, woT, 768, 6, wo_b, x, res1, nullptr, nullptr, nullptr, nullptr);

    ln_kernel<<<NTOK, 256, 0, stream>>>(res1, ln2_g, ln2_b, xn);

    gemm_kernel<2, 128><<<1536, 256, 0, stream>>>(    // 6 blocks/CU exact
        xn, w1T, 768, 24, w1_b, nullptr, nullptr, hbuf, nullptr, nullptr, nullptr);

    gemm_kernel<1, 64><<<768, 256, 0, stream>>>(      // 3 blocks/CU exact
        hbuf, w2T, 3072, 6, w2_b, res1, out, nullptr, nullptr, nullptr, nullptr);
}

// Round 9
// 453.289 us; speedup vs baseline: 1.0556x; 1.0058x over previous
//
#include <hip/hip_runtime.h>

#define T_SEQ 4096
#define D_EMB 768
#define N_HEAD 12
#define D_HEAD 64
#define D_MLP 3072
#define NTOK 8192   // B*T
#define QSCALE 0.18033688011112043f  // log2(e)/8, folded into Q at qkv epilogue

typedef __bf16 v8bf __attribute__((ext_vector_type(8)));
typedef float v4f __attribute__((ext_vector_type(4)));

template <int N> struct IC { static constexpr int value = N; };

__device__ __forceinline__ unsigned short f2bf(float f) {
    unsigned int u = __float_as_uint(f);
    unsigned int r = (u + 0x7fffu + ((u >> 16) & 1u)) >> 16;
    return (unsigned short)r;
}

__device__ __forceinline__ void g2lds16(const void* g, void* l) {
    __builtin_amdgcn_global_load_lds(
        (const __attribute__((address_space(1))) void*)g,
        (__attribute__((address_space(3))) void*)l, 16, 0, 0);
}

// chunk swizzle for 32-short (4x16B) LDS rows: 16-periodic, makes frag reads
// <=2-way bank-aliased (free) instead of 8-way (2.9x, m136)
__device__ __forceinline__ int sg(int r) { return (r ^ (r >> 2)) & 3; }

// ---------------- weight cast + transpose: fp32 [K][N] -> bf16 [N][K] --------
__global__ void tcast_kernel(const float* __restrict__ in, unsigned short* __restrict__ out,
                             int K, int N) {
    __shared__ float tile[32][33];
    int k0 = blockIdx.y * 32, n0 = blockIdx.x * 32;
    int tx = threadIdx.x, ty = threadIdx.y;
    for (int i = ty; i < 32; i += 8)
        tile[i][tx] = in[(size_t)(k0 + i) * N + n0 + tx];
    __syncthreads();
    for (int i = ty; i < 32; i += 8)
        out[(size_t)(n0 + i) * K + k0 + tx] = f2bf(tile[tx][i]);
}

// ------- V transpose, TILED: [bh][t][64] -> [bh][kt][64d][64k] (8KB tiles) ---
__global__ void vtrans_kernel(const unsigned short* __restrict__ in,
                              unsigned short* __restrict__ out) {
    __shared__ unsigned short tile[32][33];
    size_t base = (size_t)blockIdx.z * T_SEQ * D_HEAD;
    int t0 = blockIdx.x * 32, d0 = blockIdx.y * 32;
    int tx = threadIdx.x, ty = threadIdx.y;
    for (int i = ty; i < 32; i += 8)
        tile[i][tx] = in[base + (size_t)(t0 + i) * D_HEAD + d0 + tx];
    __syncthreads();
    size_t tbase = base + (size_t)(t0 >> 6) * 4096 + (t0 & 32);
    for (int i = ty; i < 32; i += 8)
        out[tbase + (size_t)(d0 + i) * 64 + tx] = tile[tx][i];
}

// ---------------- LayerNorm (768 wide), fp32 in -> bf16 out ------------------
__global__ __launch_bounds__(256) void ln_kernel(const float* __restrict__ x,
                                                 const float* __restrict__ g,
                                                 const float* __restrict__ bta,
                                                 unsigned short* __restrict__ out) {
    int row = blockIdx.x;
    const float* xr = x + (size_t)row * D_EMB;
    int tid = threadIdx.x;
    float v[3];
    float s = 0.f, s2 = 0.f;
#pragma unroll
    for (int i = 0; i < 3; i++) {
        v[i] = xr[tid + i * 256];
        s += v[i];
        s2 += v[i] * v[i];
    }
#pragma unroll
    for (int o = 1; o < 64; o <<= 1) {
        s += __shfl_xor(s, o);
        s2 += __shfl_xor(s2, o);
    }
    __shared__ float red[8];
    int wave = tid >> 6, lane = tid & 63;
    if (lane == 0) { red[wave] = s; red[wave + 4] = s2; }
    __syncthreads();
    s = red[0] + red[1] + red[2] + red[3];
    s2 = red[4] + red[5] + red[6] + red[7];
    float mu = s * (1.f / 768.f);
    float var = s2 * (1.f / 768.f) - mu * mu;
    float rstd = rsqrtf(var + 1e-5f);
#pragma unroll
    for (int i = 0; i < 3; i++) {
        int c = tid + i * 256;
        out[(size_t)row * D_EMB + c] = f2bf((v[i] - mu) * rstd * g[c] + bta[c]);
    }
}

// ---------------- GEMM: C[M,N] = A[M,K] * Bt[N,K]^T, bf16 in, fp32 acc -------
// Swapped-operand MFMA; dbuf global_load_lds staging; XCD-striped 1-D grid;
// sigma-swizzled LDS chunks (R9: kills the 8-way frag-read bank conflicts).
// MT=128: 128x128 tile (acc 4x4). MT=64: 64x128 (acc 4x2, 24KB LDS, 6 blk/CU).
template <int EPI, int MT>
__global__ __launch_bounds__(256) void gemm_kernel(
    const unsigned short* __restrict__ A, const unsigned short* __restrict__ Bt, int K,
    int Nt, const float* __restrict__ bias, const float* __restrict__ resid,
    float* __restrict__ outF, unsigned short* __restrict__ outB,
    unsigned short* __restrict__ Qb, unsigned short* __restrict__ Kb,
    unsigned short* __restrict__ Vb) {
    constexpr int NAI = (MT == 128) ? 4 : 2;     // act M-subtiles per wave
    __shared__ unsigned short As[2][MT * 32];
    __shared__ unsigned short Bs[2][4096];
    const int tid = threadIdx.x;
    const int wave = tid >> 6, lane = tid & 63;
    const int n16 = lane & 15, kq = lane >> 4;
    const int moff = (wave >> 1) * (MT / 2), noff = (wave & 1) * 64;
    // grid decode: (NTOK/MT)/8 M-tiles per XCD stripe; N inner
    const int id = blockIdx.x;
    const int xcd = id & 7, s = id >> 3;
    const int mt = xcd * (NTOK / MT / 8) + s / Nt, nt_ = s % Nt;
    const long m0 = (long)mt * MT, nb0 = (long)nt_ * 128;

    // staging thread-constants; source chunk sigma-permuted within each 64B row
    const int c0 = (wave * 2 + 0) * 64 + lane;   // B: 512 chunks, 2/thread
    const int c1 = (wave * 2 + 1) * 64 + lane;
    const int r0 = c0 >> 2, r1 = c1 >> 2;
    const unsigned short* bP0 = Bt + (nb0 + r0) * K + (((c0 & 3) ^ sg(r0)) << 3);
    const unsigned short* bP1 = Bt + (nb0 + r1) * K + (((c1 & 3) ^ sg(r1)) << 3);
    const int ca = (MT == 128) ? c0 : (wave * 64 + lane);  // A chunk index
    const int ra = ca >> 2;
    const unsigned short* aP0 = A + (m0 + ra) * K + (((ca & 3) ^ sg(ra)) << 3);
    const unsigned short* aP1 = (MT == 128)
        ? A + (m0 + r1) * K + (((c1 & 3) ^ sg(r1)) << 3) : nullptr;
    // fragment LDS short-indices (loop-invariant; sigma is 16-periodic)
    const int sn = sg(n16);
    const int fw = (noff + n16) * 32 + ((kq ^ sn) << 3);   // weight frags (Bs)
    const int fa = (moff + n16) * 32 + ((kq ^ sn) << 3);   // act frags (As)

    const v4f vzero = {0.f, 0.f, 0.f, 0.f};
    v4f acc[4][NAI];
#pragma unroll
    for (int wi = 0; wi < 4; wi++)
#pragma unroll
        for (int ai = 0; ai < NAI; ai++) acc[wi][ai] = vzero;

    auto stage = [&](auto BUFC, int kpos) {
        constexpr int nb = decltype(BUFC)::value;
        if (MT == 128) {
            g2lds16(aP0 + kpos, &As[nb][(wave * 2 + 0) * 512]);
            g2lds16(aP1 + kpos, &As[nb][(wave * 2 + 1) * 512]);
        } else {
            g2lds16(aP0 + kpos, &As[nb][wave * 512]);  // chunks wave*64..+63
        }
        g2lds16(bP0 + kpos, &Bs[nb][(wave * 2 + 0) * 512]);
        g2lds16(bP1 + kpos, &Bs[nb][(wave * 2 + 1) * 512]);
    };
    auto gstep = [&](auto BUFC, int kpos, bool pref) {
        constexpr int buf = decltype(BUFC)::value;
        __syncthreads();
        if (pref) stage(IC<buf ^ 1>{}, kpos + 32);
        v8bf wf[4], af[NAI];
#pragma unroll
        for (int i = 0; i < 4; i++) wf[i] = *(const v8bf*)(&Bs[buf][fw + i * 512]);
#pragma unroll
        for (int i = 0; i < NAI; i++) af[i] = *(const v8bf*)(&As[buf][fa + i * 512]);
#pragma unroll
        for (int wi = 0; wi < 4; wi++)
#pragma unroll
            for (int ai = 0; ai < NAI; ai++)
                acc[wi][ai] = __builtin_amdgcn_mfma_f32_16x16x32_bf16(wf[wi], af[ai],
                                                                     acc[wi][ai], 0, 0, 0);
    };

    stage(IC<0>{}, 0);
#pragma unroll 1
    for (int k0 = 0; k0 < K; k0 += 64) {
        gstep(IC<0>{}, k0, true);
        gstep(IC<1>{}, k0 + 32, k0 + 64 < K);
    }

#pragma unroll
    for (int wi = 0; wi < 4; wi++) {
#pragma unroll
        for (int ai = 0; ai < NAI; ai++) {
            const long Nb = nb0 + noff + wi * 16 + kq * 4;
            const long M = m0 + moff + ai * 16 + n16;
            if (EPI == 0) {
                int which = (int)(Nb / 768);
                int c = (int)(Nb - which * 768);
                int hh = c >> 6, ii = c & 63;
                int bb = (int)(M >> 12), t = (int)(M & 4095);
                size_t dst = (((size_t)bb * N_HEAD + hh) * T_SEQ + t) * D_HEAD + ii;
                union { uint2 u2; unsigned short us[4]; } pk;
#pragma unroll
                for (int r = 0; r < 4; r++) {
                    float v = acc[wi][ai][r];
                    if (which == 0) v *= QSCALE;
                    pk.us[r] = f2bf(v);
                }
                if (which == 0) *(uint2*)(&Qb[dst]) = pk.u2;
                else if (which == 1) *(uint2*)(&Kb[dst]) = pk.u2;
                else *(uint2*)(&Vb[dst]) = pk.u2;
            } else if (EPI == 1) {
                float4 b4 = *(const float4*)(&bias[Nb]);
                float4 r4 = *(const float4*)(&resid[M * 768 + Nb]);
                float4 o4;
                o4.x = acc[wi][ai][0] + b4.x + r4.x;
                o4.y = acc[wi][ai][1] + b4.y + r4.y;
                o4.z = acc[wi][ai][2] + b4.z + r4.z;
                o4.w = acc[wi][ai][3] + b4.w + r4.w;
                *(float4*)(&outF[M * 768 + Nb]) = o4;
            } else {
                float4 b4 = *(const float4*)(&bias[Nb]);
                union { uint2 u2; unsigned short us[4]; } pk;
#pragma unroll
                for (int r = 0; r < 4; r++) {
                    float t = acc[wi][ai][r] + ((const float*)&b4)[r];
                    pk.us[r] = f2bf(0.5f * t * (1.f + erff(t * 0.70710678118f)));
                }
                *(uint2*)(&outB[M * 3072 + Nb]) = pk.u2;
            }
        }
    }
}

// ---------------- Flash attention (causal), bf16 Q/K/Vt -> bf16 y ------------
// R5 kernel (verified 98us): 64-q blocks, PAIRED q-tiles (qt, 63-qt) -> 65
// uniform steps/block; S^T trick, pre-scaled Q, l via ones-MFMA, manual
// unroll-2 (compile-time buf), wave-private P, dbuf K/V staging.
#define PSTR 72
__global__ __launch_bounds__(256) void attn_kernel(const unsigned short* __restrict__ Q,
                                                   const unsigned short* __restrict__ Kg,
                                                   const unsigned short* __restrict__ Vt,
                                                   unsigned short* __restrict__ y) {
    __shared__ unsigned short Kt[2][4096];
    __shared__ unsigned short Vl[2][4096];
    __shared__ unsigned short Ps[4 * 16 * PSTR];
    const int tid = threadIdx.x;
    const int wave = tid >> 6, lane = tid & 63;
    const int n16 = lane & 15, kq = lane >> 4;
    const int id = blockIdx.x;
    const int xcd = id & 7, slot = id >> 3;
    const int combo = xcd * 3 + (slot >> 5);
    const int pair = slot & 31;
    const int h = combo % N_HEAD, b = combo / N_HEAD;
    const size_t hoff = (((size_t)b * N_HEAD + h) * T_SEQ) * D_HEAD;
    const unsigned short* Qh = Q + hoff;
    const unsigned short* Kh = Kg + hoff;   // [t][64], k-tile contiguous 8KB
    const unsigned short* Vh = Vt + hoff;   // [kt][64][64] tiled
    const v4f vzero = {0.f, 0.f, 0.f, 0.f};

    const int sC0 = (wave * 2 + 0) * 64 + lane;
    const int sC1 = (wave * 2 + 1) * 64 + lane;
    const int soff0 = (sC0 >> 3) * 64 + ((((sC0 & 7) ^ ((sC0 >> 3) & 7))) << 3);
    const int soff1 = (sC1 >> 3) * 64 + ((((sC1 & 7) ^ ((sC1 >> 3) & 7))) << 3);
    const int fb0 = n16 * 64 + ((kq ^ (n16 & 7)) << 3);
    const int fb1 = n16 * 64 + (((4 + kq) ^ (n16 & 7)) << 3);
    unsigned short* pwr = &Ps[wave * 1152 + n16 * PSTR + kq * 4];
    const unsigned short* prd = &Ps[wave * 1152 + n16 * PSTR + kq * 8];
    v8bf vone;
#pragma unroll
    for (int j = 0; j < 8; j++) ((unsigned short*)&vone)[j] = 0x3F80;  // bf16 1.0

    const unsigned short* knext;
    const unsigned short* vnext;
    v4f o[4], lacc;
    int qt, qglob;
    v8bf qf[2];

    auto step = [&](auto BUFC, int kt, bool pref, bool diag) {
        constexpr int buf = decltype(BUFC)::value;
        __syncthreads();  // buf's tiles ready (vmcnt), prev reads done (lgkm)
        if (pref) {
            g2lds16(knext + soff0, &Kt[buf ^ 1][(wave * 2 + 0) * 512]);
            g2lds16(knext + soff1, &Kt[buf ^ 1][(wave * 2 + 1) * 512]);
            g2lds16(vnext + soff0, &Vl[buf ^ 1][(wave * 2 + 0) * 512]);
            g2lds16(vnext + soff1, &Vl[buf ^ 1][(wave * 2 + 1) * 512]);
            knext += 4096;
            vnext += 4096;
        }
        v4f s[4];
#pragma unroll
        for (int nt = 0; nt < 4; nt++) s[nt] = vzero;
#pragma unroll
        for (int nt = 0; nt < 4; nt++) {
            v8bf k0 = *(const v8bf*)(&Kt[buf][nt * 1024 + fb0]);
            v8bf k1 = *(const v8bf*)(&Kt[buf][nt * 1024 + fb1]);
            s[nt] = __builtin_amdgcn_mfma_f32_16x16x32_bf16(k0, qf[0], s[nt], 0, 0, 0);
            s[nt] = __builtin_amdgcn_mfma_f32_16x16x32_bf16(k1, qf[1], s[nt], 0, 0, 0);
        }
#pragma unroll
        for (int nt = 0; nt < 4; nt++) {
            union { uint2 u2; __bf16 hh[4]; } pk;
#pragma unroll
            for (int r = 0; r < 4; r++) {
                float p = __builtin_amdgcn_exp2f(s[nt][r]);
                if (diag) {
                    int key = kt * 64 + nt * 16 + kq * 4 + r;
                    if (key > qglob) p = 0.f;
                }
                pk.hh[r] = (__bf16)p;
            }
            *(uint2*)(&pwr[nt * 16]) = pk.u2;
        }
#pragma unroll
        for (int ks = 0; ks < 2; ks++) {
            v8bf pa = *(const v8bf*)(&prd[ks * 32]);
            lacc = __builtin_amdgcn_mfma_f32_16x16x32_bf16(pa, vone, lacc, 0, 0, 0);
#pragma unroll
            for (int nt = 0; nt < 4; nt++) {
                v8bf vb = *(const v8bf*)(&Vl[buf][nt * 1024 + (ks ? fb1 : fb0)]);
                o[nt] = __builtin_amdgcn_mfma_f32_16x16x32_bf16(pa, vb, o[nt], 0, 0, 0);
            }
        }
    };

#pragma unroll 1
    for (int half = 0; half < 2; half++) {
        qt = half ? (63 - pair) : pair;
        qglob = qt * 64 + wave * 16 + n16;
#pragma unroll
        for (int ks = 0; ks < 2; ks++)
            qf[ks] = *(const v8bf*)(&Qh[(size_t)qglob * D_HEAD + ks * 32 + kq * 8]);
#pragma unroll
        for (int nt = 0; nt < 4; nt++) o[nt] = vzero;
        lacc = vzero;

        __syncthreads();  // prev half's readers done before restaging buf0
        g2lds16(Kh + soff0, &Kt[0][(wave * 2 + 0) * 512]);
        g2lds16(Kh + soff1, &Kt[0][(wave * 2 + 1) * 512]);
        g2lds16(Vh + soff0, &Vl[0][(wave * 2 + 0) * 512]);
        g2lds16(Vh + soff1, &Vl[0][(wave * 2 + 1) * 512]);
        knext = Kh + 4096;
        vnext = Vh + 4096;

        int kt = 0;
#pragma unroll 1
        while (kt + 2 <= qt) {
            step(IC<0>{}, kt, true, false);
            step(IC<1>{}, kt + 1, true, false);
            kt += 2;
        }
        if (kt < qt) {
            step(IC<0>{}, kt, true, false);
            step(IC<1>{}, kt + 1, false, true);
        } else {
            step(IC<0>{}, kt, false, true);
        }

        float linv[4];
#pragma unroll
        for (int r = 0; r < 4; r++) linv[r] = 1.f / lacc[r];
#pragma unroll
        for (int nt = 0; nt < 4; nt++)
#pragma unroll
            for (int r = 0; r < 4; r++) {
                int q = qt * 64 + wave * 16 + kq * 4 + r;
                float val = o[nt][r] * linv[r];
                y[((size_t)b * T_SEQ + q) * D_EMB + h * 64 + nt * 16 + n16] = f2bf(val);
            }
    }
}

// ---------------- launch -----------------------------------------------------
extern "C" void kernel_launch(void* const* d_in, const int* in_sizes, int n_in,
                              void* d_out, int out_size, void* d_ws, size_t ws_size,
                              hipStream_t stream) {
    const float* x = (const float*)d_in[0];
    const float* ln1_g = (const float*)d_in[1];
    const float* ln1_b = (const float*)d_in[2];
    const float* wqkv_w = (const float*)d_in[3];
    const float* wo_w = (const float*)d_in[4];
    const float* wo_b = (const float*)d_in[5];
    const float* ln2_g = (const float*)d_in[6];
    const float* ln2_b = (const float*)d_in[7];
    const float* w1_w = (const float*)d_in[8];
    const float* w1_b = (const float*)d_in[9];
    const float* w2_w = (const float*)d_in[10];
    const float* w2_b = (const float*)d_in[11];
    float* out = (float*)d_out;

    char* ws = (char*)d_ws;
    size_t off = 0;
    auto alloc = [&](size_t bytes) -> void* {
        void* p = ws + off;
        off += (bytes + 255) & ~(size_t)255;
        return p;
    };
    unsigned short* xn = (unsigned short*)alloc((size_t)NTOK * D_EMB * 2);
    unsigned short* wqkvT = (unsigned short*)alloc((size_t)2304 * 768 * 2);
    unsigned short* woT = (unsigned short*)alloc((size_t)768 * 768 * 2);
    unsigned short* w1T = (unsigned short*)alloc((size_t)3072 * 768 * 2);
    unsigned short* w2T = (unsigned short*)alloc((size_t)768 * 3072 * 2);
    unsigned short* Qb = (unsigned short*)alloc((size_t)NTOK * D_EMB * 2);
    unsigned short* Kb = (unsigned short*)alloc((size_t)NTOK * D_EMB * 2);
    unsigned short* Vb = (unsigned short*)alloc((size_t)NTOK * D_EMB * 2);
    unsigned short* yb = (unsigned short*)alloc((size_t)NTOK * D_EMB * 2);
    float* res1 = (float*)alloc((size_t)NTOK * D_EMB * 4);
    unsigned short* Vtb = xn;   // V^T overlay: xn dead during attn
    unsigned short* hbuf = Qb;  // w1 out overlay: spans Qb..yb (all dead then)

    dim3 tb(32, 8);
    tcast_kernel<<<dim3(2304 / 32, 768 / 32), tb, 0, stream>>>(wqkv_w, wqkvT, 768, 2304);
    tcast_kernel<<<dim3(768 / 32, 768 / 32), tb, 0, stream>>>(wo_w, woT, 768, 768);
    tcast_kernel<<<dim3(3072 / 32, 768 / 32), tb, 0, stream>>>(w1_w, w1T, 768, 3072);
    tcast_kernel<<<dim3(768 / 32, 3072 / 32), tb, 0, stream>>>(w2_w, w2T, 3072, 768);

    ln_kernel<<<NTOK, 256, 0, stream>>>(x, ln1_g, ln1_b, xn);

    gemm_kernel<0, 64><<<2304, 256, 0, stream>>>(     // 9 blocks/CU exact
        xn, wqkvT, 768, 18, nullptr, nullptr, nullptr, nullptr, Qb, Kb, Vb);

    vtrans_kernel<<<dim3(T_SEQ / 32, 2, 2 * N_HEAD), tb, 0, stream>>>(Vb, Vtb);

    attn_kernel<<<768, 256, 0, stream>>>(Qb, Kb, Vtb, yb);

    gemm_kernel<1, 64><<<768, 256, 0, stream>>>(      // 3 blocks/CU exact
        yb, woT, 768, 6, wo_b, x, res1, nullptr, nullptr, nullptr, nullptr);

    ln_kernel<<<NTOK, 256, 0, stream>>>(res1, ln2_g, ln2_b, xn);

    gemm_kernel<2, 128><<<1536, 256, 0, stream>>>(    // 6 blocks/CU exact
        xn, w1T, 768, 24, w1_b, nullptr, nullptr, hbuf, nullptr, nullptr, nullptr);

    gemm_kernel<1, 64><<<768, 256, 0, stream>>>(      // 3 blocks/CU exact
        hbuf, w2T, 3072, 6, w2_b, res1, out, nullptr, nullptr, nullptr, nullptr);
}